// Round 10
// baseline (717.210 us; speedup 1.0000x reference)
//
#include <hip/hip_runtime.h>

typedef _Float16 f16x8 __attribute__((ext_vector_type(8)));
typedef float    f32x4 __attribute__((ext_vector_type(4)));
typedef unsigned short u16;

#define VOC   128000
#define TOPIC 512
#define EMB   1024
#define BATCH 1024
#define ROWB  128   // LDS row = 64 f16 = 128 B

// XOR swizzle vs 128B-stride bank conflicts (proven rounds 2-8)
__device__ __forceinline__ int swz(int row, int kbyte) {
    return row * ROWB + (kbyte ^ ((row & 7) << 4));
}
// Bijective XCD-chunked swizzle (m204)
__device__ __forceinline__ int xcd_swz(int bid, int nwg) {
    int x = bid & 7, o = bid >> 3, q = nwg >> 3, r = nwg & 7;
    return (x < r ? x * (q + 1) : r * (q + 1) + (x - r) * q) + o;
}
union H2U { _Float16 h; u16 u; };

#define GLDS(SRC, DST) __builtin_amdgcn_global_load_lds( \
    (const __attribute__((address_space(1))) unsigned int*)(SRC), \
    (__attribute__((address_space(3))) unsigned int*)(DST), 16, 0, 0)

// ---------------------------------------------------------------------------
// K0: betat f32 -> f16 (into the ws MB that xst later overwrites with xsT)
// ---------------------------------------------------------------------------
__global__ void cvt_betat_kernel(const float* __restrict__ betat, u16* __restrict__ bt16) {
    const size_t g = (size_t)blockIdx.x * 256 + threadIdx.x;
    const float4* src = reinterpret_cast<const float4*>(betat) + g * 2;
    float4 a = src[0], b = src[1];
    f16x8 h;
    h[0]=(_Float16)a.x; h[1]=(_Float16)a.y; h[2]=(_Float16)a.z; h[3]=(_Float16)a.w;
    h[4]=(_Float16)b.x; h[5]=(_Float16)b.y; h[6]=(_Float16)b.z; h[7]=(_Float16)b.w;
    *(reinterpret_cast<f16x8*>(bt16) + g) = h;
}

// ---------------------------------------------------------------------------
// K1: W = beta0 [V,E] @ bt16^T; E = f16(exp(W)) -> first 1024 B of out rows;
//     col sums. m97-faithful: 128x128 tile, 256 thr, 4 waves (2x2), BK=64,
//     32 KB single-buffer LDS, __syncthreads drain loop.
//     B: global_load_lds (pre-swizzled source). A: f32 reg-load + cvt; next
//     tile's loads issued after the stage barrier (overlap the MFMA phase).
// ---------------------------------------------------------------------------
__global__ __launch_bounds__(256) void gemm1_kernel(
    const float* __restrict__ beta0, const u16* __restrict__ bt16,
    u16* __restrict__ Eg, float* __restrict__ sg)
{
    __shared__ char lds[32768];    // A @0 (16 KB), B @16384 (16 KB)

    const int tid  = threadIdx.x;
    const int lane = tid & 63;
    const int wid  = tid >> 6;
    const int wr = wid >> 1, wc = wid & 1;
    const int lr = lane & 15, lk = lane >> 4;
    const int srow8  = lane >> 3;
    const int schunk = ((lane & 7) ^ srow8) * 8;   // pre-swizzled 16B chunk (u16)

    const int bid = xcd_swz(blockIdx.x, gridDim.x);
    const int t0  = (bid & 3) * 128;     // 4 t-chunks co-XCD share the A panel
    const int v0  = (bid >> 2) * 128;

    const int arow = tid >> 1, ahalf = tid & 1;    // A: 32 f32 per thread
    const float* aBase = beta0 + (size_t)(v0 + arow) * EMB + ahalf * 32;

    float4 rA[8];
    f16x8  af[4], bf[4];
    f32x4  acc[4][4] = {};

    auto loadA = [&](int kt) {
        const float4* g = reinterpret_cast<const float4*>(aBase + kt * 64);
        #pragma unroll
        for (int j = 0; j < 8; ++j) rA[j] = g[j];
    };
    auto cvtA = [&]() {
        #pragma unroll
        for (int jj = 0; jj < 4; ++jj) {
            float4 x = rA[jj * 2], y = rA[jj * 2 + 1];
            f16x8 h;
            h[0]=(_Float16)x.x; h[1]=(_Float16)x.y; h[2]=(_Float16)x.z; h[3]=(_Float16)x.w;
            h[4]=(_Float16)y.x; h[5]=(_Float16)y.y; h[6]=(_Float16)y.z; h[7]=(_Float16)y.w;
            *(f16x8*)(lds + swz(arow, (ahalf * 4 + jj) * 16)) = h;
        }
    };
    auto stageB = [&](int kt) {
        #pragma unroll
        for (int g = 0; g < 4; ++g) {
            const u16* s = bt16 + (size_t)(t0 + wid * 32 + g * 8 + srow8) * EMB
                         + kt * 64 + schunk;
            GLDS(s, lds + 16384 + (wid * 32 + g * 8) * ROWB);
        }
    };

    loadA(0);

    for (int kt = 0; kt < 16; ++kt) {
        __syncthreads();               // previous compute done -> LDS writable
        stageB(kt);                    // 4 GLDS (drained by next barrier)
        cvtA();                        // rA(kt) -> LDS (rA complete: drained at sync1)
        __syncthreads();               // stage visible (vmcnt0+lgkmcnt0 drain)
        if (kt + 1 < 16) loadA(kt + 1);   // overlaps the MFMA phase below
        #pragma unroll
        for (int ks = 0; ks < 2; ++ks) {
            #pragma unroll
            for (int m = 0; m < 4; ++m)
                af[m] = *(const f16x8*)(lds + swz(wr * 64 + m * 16 + lr, ks * 64 + lk * 16));
            #pragma unroll
            for (int n = 0; n < 4; ++n)
                bf[n] = *(const f16x8*)(lds + 16384 + swz(wc * 64 + n * 16 + lr, ks * 64 + lk * 16));
            #pragma unroll
            for (int m = 0; m < 4; ++m)
                #pragma unroll
                for (int n = 0; n < 4; ++n)
                    acc[m][n] = __builtin_amdgcn_mfma_f32_16x16x32_f16(
                        af[m], bf[n], acc[m][n], 0, 0, 0);
        }
    }

    // Epilogue (proven rounds 2-3): exp -> LDS repack [128][128] -> E write + col sums
    __syncthreads();
    u16* ldsE = reinterpret_cast<u16*>(lds);
    #pragma unroll
    for (int m = 0; m < 4; ++m)
      #pragma unroll
      for (int n = 0; n < 4; ++n)
        #pragma unroll
        for (int r = 0; r < 4; ++r) {
            // C/D layout (m89/m91): col = lane&15, row = (lane>>4)*4 + reg
            const int row = wr * 64 + m * 16 + lk * 4 + r;
            const int col = wc * 64 + n * 16 + lr;
            H2U cv; cv.h = (_Float16)__expf(acc[m][n][r]);
            ldsE[row * 128 + col] = cv.u;
        }
    __syncthreads();
    {
        const int row = tid >> 1, half = tid & 1;
        u16* dst = Eg + (size_t)(v0 + row) * 2048 + t0 + half * 64;
        #pragma unroll
        for (int i = 0; i < 8; ++i) {
            int4 vv = *reinterpret_cast<const int4*>(&ldsE[row * 128 + half * 64 + i * 8]);
            *reinterpret_cast<int4*>(dst + i * 8) = vv;
        }
    }
    if (tid < 128) {
        float sum = 0.f;
        for (int r = 0; r < 128; ++r) { H2U cv; cv.u = ldsE[r * 128 + tid]; sum += (float)cv.h; }
        atomicAdd(sg + t0 + tid, sum);
    }
}

// ---------------------------------------------------------------------------
// K2: xsT[b][t] = f16( x[t][b] * 65536 / s[t] )
// ---------------------------------------------------------------------------
__global__ void xst_kernel(const float* __restrict__ x, const float* __restrict__ s,
                           u16* __restrict__ xsT)
{
    __shared__ float tile[32][33];
    const int b0 = blockIdx.x * 32, t0 = blockIdx.y * 32;
    const int tx = threadIdx.x, ty = threadIdx.y;
    tile[ty][tx] = x[(size_t)(t0 + ty) * BATCH + b0 + tx];
    __syncthreads();
    const float sc = 65536.0f / s[t0 + tx];
    H2U cv; cv.h = (_Float16)(tile[tx][ty] * sc);
    xsT[(size_t)(b0 + ty) * TOPIC + t0 + tx] = cv.u;
}

// ---------------------------------------------------------------------------
// K3: out[v, b0..] = (E @ xsT^T) * 2^-16. 128x256 tile, 512 thr, 8 waves
//     (2x4), BK=64, 48 KB single-buffer, both operands gload_lds, drain loop.
//     Dispatch 1: 256-col chunks 1..3. Dispatch 2: chunk 0 (bytes ARE E;
//     self-contained: all E GLDS drained at the last stage-barrier before
//     any out store).
// ---------------------------------------------------------------------------
__global__ __launch_bounds__(512) void gemm2_kernel(
    const u16* __restrict__ Eg, const u16* __restrict__ xsT,
    float* __restrict__ out, int c0, int nch)
{
    __shared__ char lds[49152];    // A @0 (16 KB), B @16384 (32 KB)

    const int tid  = threadIdx.x;
    const int lane = tid & 63;
    const int wid  = tid >> 6;
    const int wr = wid >> 2, wc = wid & 3;
    const int lr = lane & 15, lk = lane >> 4;
    const int srow8  = lane >> 3;
    const int schunk = ((lane & 7) ^ srow8) * 8;

    const int bid   = xcd_swz(blockIdx.x, gridDim.x);
    const int tile  = bid / nch;
    const int chunk = bid % nch;
    const int v0 = tile * 128, b0 = (c0 + chunk) * 256;

    f16x8 af[4], bf[4];
    f32x4 acc[4][4] = {};

    for (int kt = 0; kt < 8; ++kt) {
        __syncthreads();
        #pragma unroll
        for (int g = 0; g < 2; ++g) {   // A: 128 rows of E
            const u16* s = Eg + (size_t)(v0 + wid * 16 + g * 8 + srow8) * 2048
                         + kt * 64 + schunk;
            GLDS(s, lds + (wid * 16 + g * 8) * ROWB);
        }
        #pragma unroll
        for (int g = 0; g < 4; ++g) {   // B: 256 rows of xsT
            const u16* s = xsT + (size_t)(b0 + wid * 32 + g * 8 + srow8) * TOPIC
                         + kt * 64 + schunk;
            GLDS(s, lds + 16384 + (wid * 32 + g * 8) * ROWB);
        }
        __syncthreads();                // vmcnt0 drain: tile kt fully in LDS
        #pragma unroll
        for (int ks = 0; ks < 2; ++ks) {
            #pragma unroll
            for (int m = 0; m < 4; ++m)
                af[m] = *(const f16x8*)(lds + swz(wr * 64 + m * 16 + lr, ks * 64 + lk * 16));
            #pragma unroll
            for (int n = 0; n < 4; ++n)
                bf[n] = *(const f16x8*)(lds + 16384 + swz(wc * 64 + n * 16 + lr, ks * 64 + lk * 16));
            #pragma unroll
            for (int m = 0; m < 4; ++m)
                #pragma unroll
                for (int n = 0; n < 4; ++n)
                    acc[m][n] = __builtin_amdgcn_mfma_f32_16x16x32_f16(
                        af[m], bf[n], acc[m][n], 0, 0, 0);
        }
    }

    #pragma unroll
    for (int m = 0; m < 4; ++m)
      #pragma unroll
      for (int n = 0; n < 4; ++n)
        #pragma unroll
        for (int r = 0; r < 4; ++r) {
            const int row = wr * 64 + m * 16 + lk * 4 + r;
            const int col = wc * 64 + n * 16 + lr;
            out[(size_t)(v0 + row) * BATCH + b0 + col] = acc[m][n][r] * 0x1p-16f;
        }
}

// ---------------------------------------------------------------------------
extern "C" void kernel_launch(void* const* d_in, const int* in_sizes, int n_in,
                              void* d_out, int out_size, void* d_ws, size_t ws_size,
                              hipStream_t stream)
{
    const float* x     = (const float*)d_in[0];
    const float* beta0 = (const float*)d_in[1];
    const float* betat = (const float*)d_in[2];
    float* out = (float*)d_out;

    const size_t need_min = 4096 + (size_t)BATCH * TOPIC * 2;   // ~1.05 MB (proven)
    if (ws_size < need_min) return;
    float* s_g  = (float*)d_ws;
    u16*   buf1 = (u16*)((char*)d_ws + 4096);

    hipMemsetAsync(d_ws, 0, 2048, stream);                    // zero s accumulators
    cvt_betat_kernel<<<256, 256, 0, stream>>>(betat, buf1);   // buf1 = betat f16

    // E[v][t] lives in the first 1024 B of out row v (stride 4096 B)
    u16* EgO = (u16*)d_out;
    gemm1_kernel<<<4000, 256, 0, stream>>>(beta0, buf1, EgO, s_g);

    xst_kernel<<<dim3(BATCH / 32, TOPIC / 32), dim3(32, 32), 0, stream>>>(x, s_g, buf1);

    gemm2_kernel<<<3000, 512, 0, stream>>>(EgO, buf1, out, 1, 3);  // cols 256..1023
    gemm2_kernel<<<1000, 512, 0, stream>>>(EgO, buf1, out, 0, 1);  // cols 0..255 (E bytes)
}

// Round 11
// 512.444 us; speedup vs baseline: 1.3996x; 1.3996x over previous
//
#include <hip/hip_runtime.h>

typedef _Float16 f16x8 __attribute__((ext_vector_type(8)));
typedef float    f32x4 __attribute__((ext_vector_type(4)));
typedef unsigned short u16;

#define VOC   128000
#define TOPIC 512
#define EMB   1024
#define BATCH 1024

// BK=32: LDS row = 32 f16 = 64 B. Swizzle: chunk ^= (row>>1)&3 (16B chunks).
// Applied on GLDS *source* (srcChunk), on cvt ds_write addr, and on ds_read.
__device__ __forceinline__ int swz32(int row, int kbyte) {
    return row * 64 + (kbyte ^ (((row >> 1) & 3) << 4));
}
// Bijective XCD-chunked swizzle (m204)
__device__ __forceinline__ int xcd_swz(int bid, int nwg) {
    int x = bid & 7, o = bid >> 3, q = nwg >> 3, r = nwg & 7;
    return (x < r ? x * (q + 1) : r * (q + 1) + (x - r) * q) + o;
}
union H2U { _Float16 h; u16 u; };

#define SBAR() asm volatile("s_barrier" ::: "memory")
#define WVM0() asm volatile("s_waitcnt vmcnt(0)" ::: "memory")
#define WVM4() asm volatile("s_waitcnt vmcnt(4)" ::: "memory")
#define WLG0() asm volatile("s_waitcnt lgkmcnt(0)" ::: "memory")

#define GLDS(SRC, DST) __builtin_amdgcn_global_load_lds( \
    (const __attribute__((address_space(1))) unsigned int*)(SRC), \
    (__attribute__((address_space(3))) unsigned int*)(DST), 16, 0, 0)

// Per-buffer layout (32 KB): A = 256 rows x 64 B @0, B @16384. 3 buffers.
#define RD_A(BUF, MH) { _Pragma("unroll") \
    for (int m = 0; m < 4; ++m) \
        af[m] = *(const f16x8*)((BUF) + swz32(wr * 128 + (MH) * 64 + m * 16 + lr, lk * 16)); }
#define RD_B(BUF) { _Pragma("unroll") \
    for (int n = 0; n < 4; ++n) \
        bf[n] = *(const f16x8*)((BUF) + 16384 + swz32(wc * 64 + n * 16 + lr, lk * 16)); }
#define MFMA16(MH) { \
    __builtin_amdgcn_s_setprio(1); \
    _Pragma("unroll") for (int m = 0; m < 4; ++m) \
    _Pragma("unroll") for (int n = 0; n < 4; ++n) \
        acc[(MH) * 4 + m][n] = __builtin_amdgcn_mfma_f32_16x16x32_f16( \
            af[m], bf[n], acc[(MH) * 4 + m][n], 0, 0, 0); \
    __builtin_amdgcn_s_setprio(0); }

// ---------------------------------------------------------------------------
// K0: betat f32 -> f16 (into the ws MB that xst later overwrites with xsT)
// ---------------------------------------------------------------------------
__global__ void cvt_betat_kernel(const float* __restrict__ betat, u16* __restrict__ bt16) {
    const size_t g = (size_t)blockIdx.x * 256 + threadIdx.x;
    const float4* src = reinterpret_cast<const float4*>(betat) + g * 2;
    float4 a = src[0], b = src[1];
    f16x8 h;
    h[0]=(_Float16)a.x; h[1]=(_Float16)a.y; h[2]=(_Float16)a.z; h[3]=(_Float16)a.w;
    h[4]=(_Float16)b.x; h[5]=(_Float16)b.y; h[6]=(_Float16)b.z; h[7]=(_Float16)b.w;
    *(reinterpret_cast<f16x8*>(bt16) + g) = h;
}

// ---------------------------------------------------------------------------
// K1: W = beta0 @ bt16^T; E = f16(exp(W)) -> first 1024 B of out rows; colsums.
// 256x256 tile, BK=32, 32 K-tiles, 3 bufs, stage 2 tiles ahead, 1 barrier/tile.
// Per tile t: SBAR | P0: read(mh0,B), GLDS B(t+2), 16 MFMA
//                  | P1: read(mh1), load A(t+2)->regs, 16 MFMA,
//                        cvt A(t+1)->LDS (compiler reg-wait drains A(t+1)+B(t+1)),
//                        WLG0.
// Steady in-flight across each barrier: B(t+2):2 + A(t+2):4 = 6 VMEM ops.
// ---------------------------------------------------------------------------
__global__ __launch_bounds__(512) void gemm1_kernel(
    const float* __restrict__ beta0, const u16* __restrict__ bt16,
    u16* __restrict__ Eg, float* __restrict__ sg)
{
    __shared__ char lds[98304];    // 3 x 32 KB

    const int tid  = threadIdx.x;
    const int lane = tid & 63;
    const int wid  = tid >> 6;
    const int wr = wid >> 2, wc = wid & 3;
    const int lr = lane & 15, lk = lane >> 4;
    const int srcRow   = lane >> 2;                      // 0..15
    const int srcChunk = (lane & 3) ^ ((lane >> 3) & 3); // pre-swizzled source

    const int bid   = xcd_swz(blockIdx.x, gridDim.x);
    const int tile  = bid >> 1;          // 0..499
    const int chunk = bid & 1;           // t-half; pair co-XCD shares A panel
    const int v0 = tile * 256, t0 = chunk * 256;

    const int arow = tid >> 1, ahalf = tid & 1;          // 16 f32 per thread
    const float* aBase = beta0 + (size_t)(v0 + arow) * EMB + ahalf * 16;

    f32x4 acc[8][4] = {};
    f16x8 af[4], bf[4];
    float4 rEv[4], rOd[4];

#define G1_LOADA(R, KT) { const float4* gp = (const float4*)(aBase + (KT) * 32); \
    R[0] = gp[0]; R[1] = gp[1]; R[2] = gp[2]; R[3] = gp[3]; }
#define G1_CVT(R, KT1) { char* dA = lds + ((KT1) % 3) * 32768; \
    f16x8 h0, h1; \
    h0[0]=(_Float16)R[0].x; h0[1]=(_Float16)R[0].y; h0[2]=(_Float16)R[0].z; h0[3]=(_Float16)R[0].w; \
    h0[4]=(_Float16)R[1].x; h0[5]=(_Float16)R[1].y; h0[6]=(_Float16)R[1].z; h0[7]=(_Float16)R[1].w; \
    h1[0]=(_Float16)R[2].x; h1[1]=(_Float16)R[2].y; h1[2]=(_Float16)R[2].z; h1[3]=(_Float16)R[2].w; \
    h1[4]=(_Float16)R[3].x; h1[5]=(_Float16)R[3].y; h1[6]=(_Float16)R[3].z; h1[7]=(_Float16)R[3].w; \
    *(f16x8*)(dA + swz32(arow, ahalf * 32 + 0))  = h0; \
    *(f16x8*)(dA + swz32(arow, ahalf * 32 + 16)) = h1; }

    auto stageB_ = [&](int kt) {   // 2 GLDS per wave: rows wid*32 + {0,16}
        char* dst = lds + (kt % 3) * 32768 + 16384;
        const u16* s0 = bt16 + (size_t)(t0 + wid * 32 + srcRow) * EMB + kt * 32 + srcChunk * 8;
        GLDS(s0, dst + wid * 32 * 64);
        GLDS(s0 + (size_t)16 * EMB, dst + (wid * 32 + 16) * 64);
    };

    // Prologue: tile0 fully staged; tile1 stage in flight (B first, then A).
    stageB_(0);
    G1_LOADA(rEv, 0);
    G1_CVT(rEv, 0);          // reg-wait drains A(0)+B(0)
    WLG0();
    stageB_(1);
    G1_LOADA(rOd, 1);        // in flight: B(1):2, A(1):4

    // TILE(T): RC = regs of A(T+1) (loaded at T-1), RI = dest for A(T+2)
#define G1_TILE(T, RC, RI) { \
    SBAR(); \
    char* buf = lds + ((T) % 3) * 32768; \
    RD_A(buf, 0); RD_B(buf); \
    if ((T) + 2 < 32) stageB_((T) + 2); \
    MFMA16(0); \
    RD_A(buf, 1); \
    if ((T) + 2 < 32) G1_LOADA(RI, (T) + 2); \
    MFMA16(1); \
    if ((T) + 1 < 32) { G1_CVT(RC, (T) + 1); } \
    WLG0(); }

    for (int tt = 0; tt < 16; ++tt) {
        const int t = tt * 2;
        G1_TILE(t,     rOd, rEv);
        G1_TILE(t + 1, rEv, rOd);
    }

    // Epilogue (proven R4-R8): 4 chunks of 64 rows; exp -> repack -> E + colsum
    __syncthreads();
    u16* ldsE = reinterpret_cast<u16*>(lds);   // 64 x 264 u16
    float csum = 0.f;
    #pragma unroll
    for (int c = 0; c < 4; ++c) {
        if (wr == (c >> 1)) {
            const int mb = (c & 1) * 4;
            #pragma unroll
            for (int m = 0; m < 4; ++m)
              #pragma unroll
              for (int n = 0; n < 4; ++n)
                #pragma unroll
                for (int r = 0; r < 4; ++r) {
                    const int row = m * 16 + lk * 4 + r;        // 0..63
                    const int col = wc * 64 + n * 16 + lr;      // 0..255
                    H2U cv; cv.h = (_Float16)__expf(acc[mb + m][n][r]);
                    ldsE[row * 264 + col] = cv.u;
                }
        }
        __syncthreads();
        {
            const int row8 = tid >> 3, seg = tid & 7;
            const int4* sp = reinterpret_cast<const int4*>(&ldsE[row8 * 264 + seg * 32]);
            u16* dst = Eg + (size_t)(v0 + c * 64 + row8) * 2048 + t0 + seg * 32;
            int4 a0 = sp[0], a1 = sp[1], a2 = sp[2], a3 = sp[3];
            int4* dp = reinterpret_cast<int4*>(dst);
            dp[0] = a0; dp[1] = a1; dp[2] = a2; dp[3] = a3;
        }
        if (tid < 256) {
            float s = 0.f;
            for (int r = 0; r < 64; ++r) { H2U cv; cv.u = ldsE[r * 264 + tid]; s += (float)cv.h; }
            csum += s;
        }
        __syncthreads();
    }
    if (tid < 256) atomicAdd(sg + t0 + tid, csum);
}

// ---------------------------------------------------------------------------
// K2: xsT[b][t] = f16( x[t][b] * 65536 / s[t] )
// ---------------------------------------------------------------------------
__global__ void xst_kernel(const float* __restrict__ x, const float* __restrict__ s,
                           u16* __restrict__ xsT)
{
    __shared__ float tile[32][33];
    const int b0 = blockIdx.x * 32, t0 = blockIdx.y * 32;
    const int tx = threadIdx.x, ty = threadIdx.y;
    tile[ty][tx] = x[(size_t)(t0 + ty) * BATCH + b0 + tx];
    __syncthreads();
    const float sc = 65536.0f / s[t0 + tx];
    H2U cv; cv.h = (_Float16)(tile[tx][ty] * sc);
    xsT[(size_t)(b0 + ty) * TOPIC + t0 + tx] = cv.u;
}

// ---------------------------------------------------------------------------
// K3: out = (E @ xsT^T) * 2^-16. 256x256, BK=32, 16 K-tiles, 3 bufs,
// stage 2 ahead, 1 barrier/tile, counted vmcnt(4) (all ops are GLDS).
// Dispatch 1: col-chunks 1..3. Dispatch 2: chunk 0 (bytes ARE E; per-wave
// WVM0 at t=15 top + SBAR => all E reads drained before any out store).
// ---------------------------------------------------------------------------
__global__ __launch_bounds__(512) void gemm2_kernel(
    const u16* __restrict__ Eg, const u16* __restrict__ xsT,
    float* __restrict__ out, int c0, int nch)
{
    __shared__ char lds[98304];    // 3 x 32 KB

    const int tid  = threadIdx.x;
    const int lane = tid & 63;
    const int wid  = tid >> 6;
    const int wr = wid >> 2, wc = wid & 3;
    const int lr = lane & 15, lk = lane >> 4;
    const int srcRow   = lane >> 2;
    const int srcChunk = (lane & 3) ^ ((lane >> 3) & 3);

    const int bid   = xcd_swz(blockIdx.x, gridDim.x);
    const int tile  = bid / nch;
    const int chunk = bid % nch;
    const int v0 = tile * 256, b0 = (c0 + chunk) * 256;

    f32x4 acc[8][4] = {};
    f16x8 af[4], bf[4];

    auto stageA_ = [&](int kt) {
        char* dst = lds + (kt % 3) * 32768;
        const u16* s0 = Eg + (size_t)(v0 + wid * 32 + srcRow) * 2048 + kt * 32 + srcChunk * 8;
        GLDS(s0, dst + wid * 32 * 64);
        GLDS(s0 + (size_t)16 * 2048, dst + (wid * 32 + 16) * 64);
    };
    auto stageB_ = [&](int kt) {
        char* dst = lds + (kt % 3) * 32768 + 16384;
        const u16* s0 = xsT + (size_t)(b0 + wid * 32 + srcRow) * TOPIC + kt * 32 + srcChunk * 8;
        GLDS(s0, dst + wid * 32 * 64);
        GLDS(s0 + (size_t)16 * TOPIC, dst + (wid * 32 + 16) * 64);
    };

    stageA_(0); stageB_(0);    // tile0: 4 ops
    stageA_(1); stageB_(1);    // tile1: 4 ops  (8 outstanding)

    for (int t = 0; t < 16; ++t) {
        if (t < 15) { WVM4(); } else { WVM0(); }   // drain tile t; keep t+1 in flight
        SBAR();
        char* buf = lds + (t % 3) * 32768;
        RD_A(buf, 0); RD_B(buf);
        if (t + 2 < 16) stageA_(t + 2);
        MFMA16(0);
        RD_A(buf, 1);
        if (t + 2 < 16) stageB_(t + 2);
        MFMA16(1);
    }

    #pragma unroll
    for (int mh = 0; mh < 2; ++mh)
      #pragma unroll
      for (int m = 0; m < 4; ++m)
        #pragma unroll
        for (int n = 0; n < 4; ++n)
          #pragma unroll
          for (int r = 0; r < 4; ++r) {
              const int row = wr * 128 + mh * 64 + m * 16 + lk * 4 + r;
              const int col = wc * 64 + n * 16 + lr;
              out[(size_t)(v0 + row) * BATCH + b0 + col] = acc[mh * 4 + m][n][r] * 0x1p-16f;
          }
}

// ---------------------------------------------------------------------------
extern "C" void kernel_launch(void* const* d_in, const int* in_sizes, int n_in,
                              void* d_out, int out_size, void* d_ws, size_t ws_size,
                              hipStream_t stream)
{
    const float* x     = (const float*)d_in[0];
    const float* beta0 = (const float*)d_in[1];
    const float* betat = (const float*)d_in[2];
    float* out = (float*)d_out;

    const size_t need_min = 4096 + (size_t)BATCH * TOPIC * 2;   // ~1.05 MB (proven)
    if (ws_size < need_min) return;
    float* s_g  = (float*)d_ws;
    u16*   buf1 = (u16*)((char*)d_ws + 4096);

    hipMemsetAsync(d_ws, 0, 2048, stream);                    // zero s accumulators
    cvt_betat_kernel<<<256, 256, 0, stream>>>(betat, buf1);   // buf1 = betat f16

    // E[v][t] lives in the first 1024 B of out row v (stride 4096 B)
    u16* EgO = (u16*)d_out;
    gemm1_kernel<<<1000, 512, 0, stream>>>(beta0, buf1, EgO, s_g);

    xst_kernel<<<dim3(BATCH / 32, TOPIC / 32), dim3(32, 32), 0, stream>>>(x, s_g, buf1);

    gemm2_kernel<<<1500, 512, 0, stream>>>(EgO, buf1, out, 1, 3);  // cols 256..1023
    gemm2_kernel<<<500,  512, 0, stream>>>(EgO, buf1, out, 0, 1);  // cols 0..255 (E bytes)
}